// Round 8
// baseline (135.636 us; speedup 1.0000x reference)
//
#include <hip/hip_runtime.h>
#include <math.h>

#define NBATCH 32
#define S      49152
#define NF     24          // frames (2048 samples each)
#define NB     16          // biquads
#define NP     8           // fused biquad pairs -> 8 combine rounds
#define NBLK   4           // blocks per batch (R9-proven best)
#define CHUNK  16          // samples per thread
#define NCH    768         // threads per block
#define NWAVE  12          // waves per block
// R17 = R14's round-halving + R16's spill-proof combine machinery.
// Evidence: R16 gutted the second level for only -3.5us -> per-round cost is
// the replicated serial core (PhaseA chain + KS + barrier + PhaseC) at ~10.7k
// cy/round x 16 rounds. Round WEIGHT changes are cheap (R16), round COUNT is
// the divisor (R11's 15x amplification of per-round additions). R14 tested
// 8 rounds but spilled (213MB scratch) because its combine carried matrices.
// R17 fuses pairs into 4-state sections with ALL matrices precomputed at
// init (param-only, replicated per block): per-frame Tp^16 (KS base),
// Tp^1024 (wave aggregates), prefixes P_w, cross-quarter W_k. The runtime
// combine carries only 4-float constants; KS/binexp square Tp^16 in
// registers (12 floats, R16-proven). 8 barriers, 8 L2 handshakes.
// Health: WRITE ~7.1MB (scratch check), VGPR <= ~110.

__device__ __forceinline__ float clampf(float x, float lo, float hi) {
    return fminf(fmaxf(x, lo), hi);
}

// 16 named scalar signal registers (SSA-guaranteed; arrays spill).
#define FOREACH_S(OP) \
    OP(s00) OP(s01) OP(s02) OP(s03) OP(s04) OP(s05) OP(s06) OP(s07) \
    OP(s08) OP(s09) OP(s10) OP(s11) OP(s12) OP(s13) OP(s14) OP(s15)

#define DECL_S(x) float x;

// Phase A step: state only (fused pair; identical arithmetic to sequential).
#define STEPA2(x) { \
    const float y1_  = fmaf(c0a, j1, fmaf(c1a, j2, c2a * (x))); \
    const float nj1_ = fmaf(t00a, j1, fmaf(t01a, j2, b0a * (x))); \
    const float nj2_ = fmaf(t10a, j1, fmaf(t11a, j2, b1a * (x))); \
    const float nk1_ = fmaf(t00b, k1, fmaf(t01b, k2, b0b * y1_)); \
    const float nk2_ = fmaf(t10b, k1, fmaf(t11b, k2, b1b * y1_)); \
    j1 = nj1_; j2 = nj2_; k1 = nk1_; k2 = nk2_; }

// Phase C step: output + state, in place.
#define STEPC2(x) { \
    const float y1_  = fmaf(c0a, j1, fmaf(c1a, j2, c2a * (x))); \
    const float y2_  = fmaf(c0b, k1, fmaf(c1b, k2, c2b * y1_)); \
    const float nj1_ = fmaf(t00a, j1, fmaf(t01a, j2, b0a * (x))); \
    const float nj2_ = fmaf(t10a, j1, fmaf(t11a, j2, b1a * (x))); \
    const float nk1_ = fmaf(t00b, k1, fmaf(t01b, k2, b0b * y1_)); \
    const float nk2_ = fmaf(t10b, k1, fmaf(t11b, k2, b1b * y1_)); \
    (x) = y2_; j1 = nj1_; j2 = nj2_; k1 = nk1_; k2 = nk2_; }

struct Aff { float t00, t01, t10, t11, b0, b1, c0, c1, c2; };

__device__ __forceinline__ Aff biquad_affine(int f, const float* P, int fr) {
    const float fn = P[(3 * f + 0) * NF + fr];
    const float gn = P[(3 * f + 1) * NF + fr];
    const float qn = P[(3 * f + 2) * NF + fr];

    float Q = __expf(-0.69314718f + qn * 3.4657359f);
    Q = clampf(Q, 0.1f, 100.0f);

    float lo, hi;
    int type;                        // 0 hp, 1 lp, 2 peak, 3 lowshelf, 4 highshelf
    if      (f == 0)  { lo = 20.0f;   hi = 500.0f;   type = 0; }
    else if (f == 15) { lo = 5000.0f; hi = 20000.0f; type = 1; }
    else if (f == 1)  { lo = 50.0f;   hi = 16000.0f; type = 3; }
    else if (f == 14) { lo = 50.0f;   hi = 16000.0f; type = 4; }
    else              { lo = 100.0f;  hi = 15000.0f; type = 2; }

    const float fc = __expf(__logf(lo) + fn * (__logf(hi) - __logf(lo)));
    float g_ = __tanf((float)M_PI * fc / 96000.0f);   // angle <= 0.655 rad
    g_ = clampf(g_, 1e-6f, 100.0f);
    const float gdb = -24.0f + 48.0f * gn;

    float a1, a2, a3, m0, m1, m2;
    if (type == 0 || type == 1) {
        const float k = 1.0f / Q;
        a1 = 1.0f / (1.0f + g_ * (g_ + k)); a2 = g_ * a1; a3 = g_ * a2;
        if (type == 0) { m0 = 1.0f; m1 = -k;   m2 = -1.0f; }
        else           { m0 = 0.0f; m1 = 0.0f; m2 = 1.0f;  }
    } else if (type == 2) {
        const float A = __expf(gdb * (2.30258509f / 40.0f));
        const float k = (gdb >= 0.0f) ? 1.0f / (Q * A) : A / Q;
        a1 = 1.0f / (1.0f + g_ * (g_ + k)); a2 = g_ * a1; a3 = g_ * a2;
        m0 = 1.0f; m1 = k * (A * A - 1.0f); m2 = 0.0f;
    } else {
        const float A  = __expf(gdb * (2.30258509f / 40.0f));
        const float sA = sqrtf(A);
        const float k  = 1.0f / Q;
        float gs;
        if (type == 3) gs = (gdb >= 0.0f) ? g_ / sA : g_ * sA;
        else           gs = (gdb >= 0.0f) ? g_ * sA : g_ / sA;
        a1 = 1.0f / (1.0f + gs * (gs + k)); a2 = gs * a1; a3 = gs * a2;
        if (type == 3) { m0 = 1.0f;  m1 = k * (A - 1.0f);      m2 = A * A - 1.0f; }
        else           { m0 = A * A; m1 = k * (1.0f - A) * A;  m2 = 1.0f - A * A; }
    }

    const float q2 = a2 * a2 + a3;
    Aff r;
    r.t00 = 2.0f * a1 - 1.0f;
    r.t01 = -2.0f * a2;
    r.t10 = 2.0f * a1 * a2;
    r.t11 = 1.0f - 2.0f * q2;
    r.b0  = 2.0f * a2;
    r.b1  = 2.0f * q2;
    r.c0  = a1 * (m1 + m2 * a2);
    r.c1  = m2 * (1.0f - q2) - m1 * a2;
    r.c2  = m0 + m1 * a2 + m2 * q2;
    return r;
}

// 3-block lower-triangular 4x4: [[A,0],[X,B]] of 2x2 blocks.
struct B3 {
    float a00, a01, a10, a11;
    float x00, x01, x10, x11;
    float b00, b01, b10, b11;
};

__device__ __forceinline__ void b3_square(B3& m) {
    const float na00 = m.a00 * m.a00 + m.a01 * m.a10;
    const float na01 = m.a00 * m.a01 + m.a01 * m.a11;
    const float na10 = m.a10 * m.a00 + m.a11 * m.a10;
    const float na11 = m.a10 * m.a01 + m.a11 * m.a11;
    const float nx00 = m.x00 * m.a00 + m.x01 * m.a10 + m.b00 * m.x00 + m.b01 * m.x10;
    const float nx01 = m.x00 * m.a01 + m.x01 * m.a11 + m.b00 * m.x01 + m.b01 * m.x11;
    const float nx10 = m.x10 * m.a00 + m.x11 * m.a10 + m.b10 * m.x00 + m.b11 * m.x10;
    const float nx11 = m.x10 * m.a01 + m.x11 * m.a11 + m.b10 * m.x01 + m.b11 * m.x11;
    const float nb00 = m.b00 * m.b00 + m.b01 * m.b10;
    const float nb01 = m.b00 * m.b01 + m.b01 * m.b11;
    const float nb10 = m.b10 * m.b00 + m.b11 * m.b10;
    const float nb11 = m.b10 * m.b01 + m.b11 * m.b11;
    m.a00 = na00; m.a01 = na01; m.a10 = na10; m.a11 = na11;
    m.x00 = nx00; m.x01 = nx01; m.x10 = nx10; m.x11 = nx11;
    m.b00 = nb00; m.b01 = nb01; m.b10 = nb10; m.b11 = nb11;
}

// compose: result = m2 after m1  (T = T2 * T1)
__device__ __forceinline__ B3 b3_compose(const B3& m2, const B3& m1) {
    B3 r;
    r.a00 = m2.a00 * m1.a00 + m2.a01 * m1.a10;
    r.a01 = m2.a00 * m1.a01 + m2.a01 * m1.a11;
    r.a10 = m2.a10 * m1.a00 + m2.a11 * m1.a10;
    r.a11 = m2.a10 * m1.a01 + m2.a11 * m1.a11;
    r.x00 = m2.x00 * m1.a00 + m2.x01 * m1.a10 + m2.b00 * m1.x00 + m2.b01 * m1.x10;
    r.x01 = m2.x00 * m1.a01 + m2.x01 * m1.a11 + m2.b00 * m1.x01 + m2.b01 * m1.x11;
    r.x10 = m2.x10 * m1.a00 + m2.x11 * m1.a10 + m2.b10 * m1.x00 + m2.b11 * m1.x10;
    r.x11 = m2.x10 * m1.a01 + m2.x11 * m1.a11 + m2.b10 * m1.x01 + m2.b11 * m1.x11;
    r.b00 = m2.b00 * m1.b00 + m2.b01 * m1.b10;
    r.b01 = m2.b00 * m1.b01 + m2.b01 * m1.b11;
    r.b10 = m2.b10 * m1.b00 + m2.b11 * m1.b10;
    r.b11 = m2.b10 * m1.b01 + m2.b11 * m1.b11;
    return r;
}

__device__ __forceinline__ void b3_store(float4* dst, const B3& m) {
    dst[0] = make_float4(m.a00, m.a01, m.a10, m.a11);
    dst[1] = make_float4(m.x00, m.x01, m.x10, m.x11);
    dst[2] = make_float4(m.b00, m.b01, m.b10, m.b11);
}

__device__ __forceinline__ B3 b3_load(const float4* src) {
    B3 m;
    const float4 q0 = src[0], q1 = src[1], q2 = src[2];
    m.a00 = q0.x; m.a01 = q0.y; m.a10 = q0.z; m.a11 = q0.w;
    m.x00 = q1.x; m.x01 = q1.y; m.x10 = q1.z; m.x11 = q1.w;
    m.b00 = q2.x; m.b01 = q2.y; m.b10 = q2.z; m.b11 = q2.w;
    return m;
}

__global__ __launch_bounds__(NCH, 3)
void biquad_chain_kernel(const float* __restrict__ audio,
                         const float* __restrict__ params,
                         float* __restrict__ out,
                         unsigned int* __restrict__ ws)
{
    __shared__ __align__(16) float scp[NP][6][20];   // fused affine, 18 used
    __shared__ float4 sM16[NP][6][3];     // Tp^16 (KS/binexp base), local frames
    __shared__ float4 sMw[NP][6][3];      // Tp^1024 (wave aggregates), local
    __shared__ float4 sPm[NP][NWAVE][3];  // exclusive wave prefixes P_w
    __shared__ float4 sWm[NP][3][3];      // cross-quarter fold matrices W_k
    __shared__ float4 sT2048[NP][NF][3];  // frame aggregates (init/prefix only)
    __shared__ float4 sagg[2][NWAVE];     // runtime wave constants (dbuf)
    __shared__ float4 sv2[NWAVE];         // per-wave incoming 4-state
    __shared__ float  sgain[2][NF];       // [0]=in, [1]=out
    __shared__ unsigned int sflag[NP];    // per-stage sv-ready flag

    const int t       = threadIdx.x;
    // XCD co-location swizzle: all 4 quarters of a batch on one XCD.
    const int xcd     = blockIdx.x & 7;
    const int slot_   = blockIdx.x >> 3;
    const int bt      = xcd * 4 + (slot_ & 3);   // batch
    const int quarter = slot_ >> 2;              // which quarter of the signal
    const int lane    = t & 63;
    const int wave    = t >> 6;
    const int lf      = wave >> 1;               // local frame 0..5
    const int frame   = quarter * 6 + lf;        // global frame

    // ------------- init: fused pair transitions + powers (t < 192) ---------
    if (t < NP * NF) {
        const int p  = t / NF;
        const int fr = t % NF;
        const float* P = params + (size_t)bt * 50 * NF;
        const Aff A = biquad_affine(2 * p,     P, fr);
        const Aff B = biquad_affine(2 * p + 1, P, fr);

        B3 m;
        m.a00 = A.t00; m.a01 = A.t01; m.a10 = A.t10; m.a11 = A.t11;
        m.x00 = B.b0 * A.c0; m.x01 = B.b0 * A.c1;
        m.x10 = B.b1 * A.c0; m.x11 = B.b1 * A.c1;
        m.b00 = B.t00; m.b01 = B.t01; m.b10 = B.t10; m.b11 = B.t11;

        #pragma unroll
        for (int i = 0; i < 4; i++) b3_square(m);          // Tp^16
        const int lfr = fr - quarter * 6;
        const bool local = (lfr >= 0 && lfr < 6);
        if (local) {
            float* d = scp[p][lfr];
            d[0]  = A.t00; d[1]  = A.t01; d[2]  = A.t10; d[3]  = A.t11;
            d[4]  = A.b0;  d[5]  = A.b1;  d[6]  = A.c0;  d[7]  = A.c1;
            d[8]  = A.c2;  d[9]  = B.t00; d[10] = B.t01; d[11] = B.t10;
            d[12] = B.t11; d[13] = B.b0;  d[14] = B.b1;  d[15] = B.c0;
            d[16] = B.c1;  d[17] = B.c2;  d[18] = 0.0f;  d[19] = 0.0f;
            b3_store(sM16[p][lfr], m);
        }
        #pragma unroll
        for (int i = 0; i < 6; i++) b3_square(m);          // Tp^1024
        if (local) b3_store(sMw[p][lfr], m);
        b3_square(m);                                      // Tp^2048
        b3_store(sT2048[p][fr], m);
    }
    if (t >= 192 && t < 192 + 2 * NF) {
        const int idx = t - 192;
        const int which = idx / NF;
        const int fr    = idx % NF;
        const float* P = params + (size_t)bt * 50 * NF;
        const float p  = P[(48 + which) * NF + fr];
        const float db = -60.0f + 60.0f * p;
        sgain[which][fr] = __expf(db * (2.30258509f / 20.0f));
    }
    if (t < NP) sflag[t] = 0u;
    __syncthreads();

    // ------------- prefix assembly (t < 8, one per pair) -------------------
    if (t < NP) {
        const int p = t;
        B3 Q;   // running product (identity)
        Q.a00 = 1.0f; Q.a01 = 0.0f; Q.a10 = 0.0f; Q.a11 = 1.0f;
        Q.x00 = 0.0f; Q.x01 = 0.0f; Q.x10 = 0.0f; Q.x11 = 0.0f;
        Q.b00 = 1.0f; Q.b01 = 0.0f; Q.b10 = 0.0f; Q.b11 = 1.0f;
        #pragma unroll
        for (int k = 0; k < 6; k++) {
            b3_store(sPm[p][2 * k], Q);
            const B3 mw = b3_load(sMw[p][k]);
            b3_store(sPm[p][2 * k + 1], b3_compose(mw, Q));
            const B3 g = b3_load(sT2048[p][quarter * 6 + k]);
            Q = b3_compose(g, Q);
        }
        if (quarter > 0) {
            B3 R;   // W_{q-1} = I
            R.a00 = 1.0f; R.a01 = 0.0f; R.a10 = 0.0f; R.a11 = 1.0f;
            R.x00 = 0.0f; R.x01 = 0.0f; R.x10 = 0.0f; R.x11 = 0.0f;
            R.b00 = 1.0f; R.b01 = 0.0f; R.b10 = 0.0f; R.b11 = 1.0f;
            for (int k = quarter - 1; k >= 0; k--) {
                b3_store(sWm[p][k], R);
                if (k > 0) {
                    B3 bk;
                    bk.a00 = 1.0f; bk.a01 = 0.0f; bk.a10 = 0.0f; bk.a11 = 1.0f;
                    bk.x00 = 0.0f; bk.x01 = 0.0f; bk.x10 = 0.0f; bk.x11 = 0.0f;
                    bk.b00 = 1.0f; bk.b01 = 0.0f; bk.b10 = 0.0f; bk.b11 = 1.0f;
                    #pragma unroll
                    for (int mi = 0; mi < 6; mi++) {
                        const B3 g = b3_load(sT2048[p][6 * k + mi]);
                        bk = b3_compose(g, bk);
                    }
                    R = b3_compose(R, bk);
                }
            }
        }
    }
    __syncthreads();

    // ---------------- load chunk (with input gain) ----------------
    FOREACH_S(DECL_S)
    {
        const float ing = sgain[0][frame];
        const float* base = audio + (size_t)bt * S
                          + (size_t)(quarter * NCH + t) * CHUNK;
        float4 q;
        q = *(const float4*)(base +  0); s00 = q.x*ing; s01 = q.y*ing; s02 = q.z*ing; s03 = q.w*ing;
        q = *(const float4*)(base +  4); s04 = q.x*ing; s05 = q.y*ing; s06 = q.z*ing; s07 = q.w*ing;
        q = *(const float4*)(base +  8); s08 = q.x*ing; s09 = q.y*ing; s10 = q.z*ing; s11 = q.w*ing;
        q = *(const float4*)(base + 12); s12 = q.x*ing; s13 = q.y*ing; s14 = q.z*ing; s15 = q.w*ing;
    }

    // ---------------- 8 fused rounds ----------------
    #pragma unroll 1
    for (int f = 0; f < NP; f++) {
        const float* d = scp[f][lf];
        const float4 q0 = *(const float4*)(d +  0);
        const float4 q1 = *(const float4*)(d +  4);
        const float4 q2 = *(const float4*)(d +  8);
        const float4 q3 = *(const float4*)(d + 12);
        const float t00a = q0.x, t01a = q0.y, t10a = q0.z, t11a = q0.w;
        const float b0a  = q1.x, b1a  = q1.y, c0a  = q1.z, c1a  = q1.w;
        const float c2a  = q2.x, t00b = q2.y, t01b = q2.z, t10b = q2.w;
        const float t11b = q3.x, b0b  = q3.y, b1b  = q3.z, c0b  = q3.w;

        // Phase A: zero-state run -> 4-dim affine constant
        float j1 = 0.0f, j2 = 0.0f, k1 = 0.0f, k2 = 0.0f;
        FOREACH_S(STEPA2)

        // constants-only KS; wave-uniform M = Tp^16 squared in registers
        B3 m = b3_load(sM16[f][lf]);
        float Ac1 = j1, Ac2 = j2, Ac3 = k1, Ac4 = k2;
        #pragma unroll
        for (int dd = 1; dd < 64; dd <<= 1) {
            const float l1 = __shfl_up(Ac1, dd);
            const float l2 = __shfl_up(Ac2, dd);
            const float l3 = __shfl_up(Ac3, dd);
            const float l4 = __shfl_up(Ac4, dd);
            if (lane >= dd) {
                const float n1 = fmaf(m.a00, l1, fmaf(m.a01, l2, Ac1));
                const float n2 = fmaf(m.a10, l1, fmaf(m.a11, l2, Ac2));
                const float n3 = fmaf(m.x00, l1, fmaf(m.x01, l2, fmaf(m.b00, l3, fmaf(m.b01, l4, Ac3))));
                const float n4 = fmaf(m.x10, l1, fmaf(m.x11, l2, fmaf(m.b10, l3, fmaf(m.b11, l4, Ac4))));
                Ac1 = n1; Ac2 = n2; Ac3 = n3; Ac4 = n4;
            }
            if (dd < 32) b3_square(m);
        }
        // Ac at lane 63 = wave aggregate constant

        const int buf = f & 1;
        if (lane == 63) sagg[buf][wave] = make_float4(Ac1, Ac2, Ac3, Ac4);
        __syncthreads();   // one barrier per round

        const unsigned int tag = (unsigned int)(f + 1);
        unsigned int* stagebase = ws + ((size_t)(bt * NP + f) * NBLK) * 8;

        if (wave == 0) {
            // predicated 12-step constants fold (precomputed M_w from LDS)
            float Pc1 = 0.0f, Pc2 = 0.0f, Pc3 = 0.0f, Pc4 = 0.0f;
            #pragma unroll
            for (int j = 0; j < NWAVE; j++) {
                const float4 a = sagg[buf][j];
                const B3 mw = b3_load(sMw[f][j >> 1]);
                if (lane > j) {
                    const float n1 = fmaf(mw.a00, Pc1, fmaf(mw.a01, Pc2, a.x));
                    const float n2 = fmaf(mw.a10, Pc1, fmaf(mw.a11, Pc2, a.y));
                    const float n3 = fmaf(mw.x00, Pc1, fmaf(mw.x01, Pc2, fmaf(mw.b00, Pc3, fmaf(mw.b01, Pc4, a.z))));
                    const float n4 = fmaf(mw.x10, Pc1, fmaf(mw.x11, Pc2, fmaf(mw.b10, Pc3, fmaf(mw.b11, Pc4, a.w))));
                    Pc1 = n1; Pc2 = n2; Pc3 = n3; Pc4 = n4;
                }
            }

            // publish block-own inclusive constant (lane 12) ASAP
            if (quarter < NBLK - 1 && lane == NWAVE) {
                unsigned int* slot = stagebase + quarter * 8;
                float* dp = (float*)(slot + 1);
                __hip_atomic_store(&dp[0], Pc1, __ATOMIC_RELAXED, __HIP_MEMORY_SCOPE_AGENT);
                __hip_atomic_store(&dp[1], Pc2, __ATOMIC_RELAXED, __HIP_MEMORY_SCOPE_AGENT);
                __hip_atomic_store(&dp[2], Pc3, __ATOMIC_RELAXED, __HIP_MEMORY_SCOPE_AGENT);
                __hip_atomic_store(&dp[3], Pc4, __ATOMIC_RELAXED, __HIP_MEMORY_SCOPE_AGENT);
                __hip_atomic_store(slot, tag, __ATOMIC_RELEASE, __HIP_MEMORY_SCOPE_AGENT);
            }

            // block incoming state: parallel polls + precomputed-W fold
            float S1 = 0.0f, S2 = 0.0f, S3 = 0.0f, S4 = 0.0f;
            if (quarter > 0) {
                float u1 = 0.0f, u2 = 0.0f, u3 = 0.0f, u4 = 0.0f;
                if (lane < quarter) {
                    unsigned int* slot = stagebase + lane * 8;
                    while (__hip_atomic_load(slot, __ATOMIC_ACQUIRE, __HIP_MEMORY_SCOPE_AGENT) != tag) {
                        __builtin_amdgcn_s_sleep(1);
                    }
                    const float* dp = (const float*)(slot + 1);
                    const float c1 = __hip_atomic_load(&dp[0], __ATOMIC_RELAXED, __HIP_MEMORY_SCOPE_AGENT);
                    const float c2 = __hip_atomic_load(&dp[1], __ATOMIC_RELAXED, __HIP_MEMORY_SCOPE_AGENT);
                    const float c3 = __hip_atomic_load(&dp[2], __ATOMIC_RELAXED, __HIP_MEMORY_SCOPE_AGENT);
                    const float c4 = __hip_atomic_load(&dp[3], __ATOMIC_RELAXED, __HIP_MEMORY_SCOPE_AGENT);
                    const B3 w = b3_load(sWm[f][lane]);
                    u1 = fmaf(w.a00, c1, w.a01 * c2);
                    u2 = fmaf(w.a10, c1, w.a11 * c2);
                    u3 = fmaf(w.x00, c1, fmaf(w.x01, c2, fmaf(w.b00, c3, w.b01 * c4)));
                    u4 = fmaf(w.x10, c1, fmaf(w.x11, c2, fmaf(w.b10, c3, w.b11 * c4)));
                }
                S1 = __shfl(u1, 0); S2 = __shfl(u2, 0);
                S3 = __shfl(u3, 0); S4 = __shfl(u4, 0);
                if (quarter > 1) {
                    S1 += __shfl(u1, 1); S2 += __shfl(u2, 1);
                    S3 += __shfl(u3, 1); S4 += __shfl(u4, 1);
                }
                if (quarter > 2) {
                    S1 += __shfl(u1, 2); S2 += __shfl(u2, 2);
                    S3 += __shfl(u3, 2); S4 += __shfl(u4, 2);
                }
            }

            // per-wave incoming state v = P_w * S0 + Pc_w
            if (lane < NWAVE) {
                const B3 pm = b3_load(sPm[f][lane]);
                const float v1 = fmaf(pm.a00, S1, fmaf(pm.a01, S2, Pc1));
                const float v2 = fmaf(pm.a10, S1, fmaf(pm.a11, S2, Pc2));
                const float v3 = fmaf(pm.x00, S1, fmaf(pm.x01, S2, fmaf(pm.b00, S3, fmaf(pm.b01, S4, Pc3))));
                const float v4 = fmaf(pm.x10, S1, fmaf(pm.x11, S2, fmaf(pm.b10, S3, fmaf(pm.b11, S4, Pc4))));
                sv2[lane] = make_float4(v1, v2, v3, v4);
            }
            if (lane == 0) {
                __hip_atomic_store(&sflag[f], tag, __ATOMIC_RELEASE,
                                   __HIP_MEMORY_SCOPE_WORKGROUP);
            }
        } else {
            while (__hip_atomic_load(&sflag[f], __ATOMIC_ACQUIRE,
                                     __HIP_MEMORY_SCOPE_WORKGROUP) != tag)
                __builtin_amdgcn_s_sleep(1);
        }

        const float4 v = sv2[wave];

        // lane-exclusive constants
        float ce1 = __shfl_up(Ac1, 1);
        float ce2 = __shfl_up(Ac2, 1);
        float ce3 = __shfl_up(Ac3, 1);
        float ce4 = __shfl_up(Ac4, 1);
        if (lane == 0) { ce1 = 0.0f; ce2 = 0.0f; ce3 = 0.0f; ce4 = 0.0f; }

        // distribute: ic = M^lane * v + ce via binary exponentiation
        float w1 = v.x, w2 = v.y, w3 = v.z, w4 = v.w;
        B3 pw = b3_load(sM16[f][lf]);
        #pragma unroll
        for (int b = 0; b < 6; b++) {
            if (lane & (1 << b)) {
                const float n1 = fmaf(pw.a00, w1, pw.a01 * w2);
                const float n2 = fmaf(pw.a10, w1, pw.a11 * w2);
                const float n3 = fmaf(pw.x00, w1, fmaf(pw.x01, w2, fmaf(pw.b00, w3, pw.b01 * w4)));
                const float n4 = fmaf(pw.x10, w1, fmaf(pw.x11, w2, fmaf(pw.b10, w3, pw.b11 * w4)));
                w1 = n1; w2 = n2; w3 = n3; w4 = n4;
            }
            if (b < 5) b3_square(pw);
        }
        j1 = w1 + ce1;
        j2 = w2 + ce2;
        k1 = w3 + ce3;
        k2 = w4 + ce4;

        // Phase C: true run from incoming state, write outputs in place
        const float2 qc = *(const float2*)(d + 16);
        const float c1b = qc.x, c2b = qc.y;
        FOREACH_S(STEPC2)
    }

    // ---------------- store (with output gain) ----------------
    {
        const float og = sgain[1][frame];
        float* base = out + (size_t)bt * S + (size_t)(quarter * NCH + t) * CHUNK;
        float4 q;
        q.x = s00*og; q.y = s01*og; q.z = s02*og; q.w = s03*og; *(float4*)(base +  0) = q;
        q.x = s04*og; q.y = s05*og; q.z = s06*og; q.w = s07*og; *(float4*)(base +  4) = q;
        q.x = s08*og; q.y = s09*og; q.z = s10*og; q.w = s11*og; *(float4*)(base +  8) = q;
        q.x = s12*og; q.y = s13*og; q.z = s14*og; q.w = s15*og; *(float4*)(base + 12) = q;
    }
}

extern "C" void kernel_launch(void* const* d_in, const int* in_sizes, int n_in,
                              void* d_out, int out_size, void* d_ws, size_t ws_size,
                              hipStream_t stream)
{
    const float* audio  = (const float*)d_in[0];
    const float* params = (const float*)d_in[1];
    float* out = (float*)d_out;
    unsigned int* ws = (unsigned int*)d_ws;
    biquad_chain_kernel<<<NBLK * NBATCH, NCH, 0, stream>>>(audio, params, out, ws);
}

// Round 9
// 130.664 us; speedup vs baseline: 1.0381x; 1.0381x over previous
//
#include <hip/hip_runtime.h>
#include <math.h>

#define NBATCH 32
#define S      49152
#define NF     24          // frames (2048 samples each)
#define NB     16          // biquads
#define NBLK   4           // blocks per batch (R9-proven best)
#define CHUNK  16          // samples per thread (R9-proven; 32 spills)
#define NCH    768         // threads per block
#define NWAVE  12          // waves per block
// R18 = R16 (best clean, 71.5us) minus redundant work. Evidence R16 vs R17:
// wall tracks TOTAL ISSUE + serial chain (R17: 8 heavier rounds = 85us worse
// than 16 light rounds at 71.5us), consistent with a low effective clock for
// this latency-bound kernel. So: same structure, less arithmetic.
//  (1) KS/binexp power matrices (T^16)^(2^j) precomputed at init into LDS
//      (param-only) -- removes 11 wave-uniform in-register squarings/round
//      (~88 inst/thread/round) for 12 broadcast ds_read_b128.
//  (2) PhaseC(f) fused with PhaseA(f+1): ONE 16-sample loop per round
//      (y of stage f feeds stage f+1's zero-state accum in-iteration).
//      Same FLOPs, half the per-round serial sample-chain; output
//      arithmetic order identical to STEPC (no numerics change).
// Health: WRITE ~7.1MB (scratch check), VGPR 60-80, absmax 0.015625.

__device__ __forceinline__ float clampf(float x, float lo, float hi) {
    return fminf(fmaxf(x, lo), hi);
}

// 16 named scalar signal registers (SSA-guaranteed; arrays spill).
#define FOREACH_S(OP) \
    OP(s00) OP(s01) OP(s02) OP(s03) OP(s04) OP(s05) OP(s06) OP(s07) \
    OP(s08) OP(s09) OP(s10) OP(s11) OP(s12) OP(s13) OP(s14) OP(s15)

#define DECL_S(x) float x;

// Prologue Phase A step (stage 0): state only, coeffs in u/e regs.
#define STEPA(x) { \
    const float n1_ = fmaf(u00, ja, fmaf(u01, jb, e0 * (x))); \
    const float n2_ = fmaf(u10, ja, fmaf(u11, jb, e1 * (x))); \
    ja = n1_; jb = n2_; }

// Final round: output + state only.
#define STEPC(x) { \
    const float y_  = fmaf(c0, ic1, fmaf(c1, ic2, c2v * (x))); \
    const float n1_ = fmaf(t00, ic1, fmaf(t01, ic2, b0v * (x))); \
    const float n2_ = fmaf(t10, ic1, fmaf(t11, ic2, b1v * (x))); \
    (x) = y_; ic1 = n1_; ic2 = n2_; }

// Fused: stage f output + state, AND stage f+1 zero-state accumulation.
#define STEPF(x) { \
    const float y_  = fmaf(c0, ic1, fmaf(c1, ic2, c2v * (x))); \
    const float n1_ = fmaf(t00, ic1, fmaf(t01, ic2, b0v * (x))); \
    const float n2_ = fmaf(t10, ic1, fmaf(t11, ic2, b1v * (x))); \
    (x) = y_; ic1 = n1_; ic2 = n2_; \
    const float m1_ = fmaf(u00, ja, fmaf(u01, jb, e0 * y_)); \
    const float m2_ = fmaf(u10, ja, fmaf(u11, jb, e1 * y_)); \
    ja = m1_; jb = m2_; }

__global__ __launch_bounds__(NCH, 3)
void biquad_chain_kernel(const float* __restrict__ audio,
                         const float* __restrict__ params,
                         float* __restrict__ out,
                         unsigned int* __restrict__ ws)
{
    __shared__ __align__(16) float sc[NB][6][12];  // affine: T(4) b(2) c(3), local frames
    __shared__ float4 spow[NB][6][6];     // (T^16)^(2^j), j=0..5, local frames
    __shared__ float4 sMw[NB][6];         // T^1024 per local frame (wave aggregates)
    __shared__ float4 sPm[NB][NWAVE][1];  // exclusive wave-prefix P_w
    __shared__ float4 sWm[NB][3];         // pred-quarter fold matrices W_k
    __shared__ float4 sT2048[NB][NF];     // frame aggregates (init/prefix only)
    __shared__ float  sgain[2][NF];       // [0]=in gain, [1]=out gain
    __shared__ float2 sagg[2][NWAVE];     // runtime wave constants (dbuf)
    __shared__ float2 sv[NWAVE];          // per-wave incoming state
    __shared__ unsigned int sflag[NB];    // per-stage sv-ready flag

    const int t       = threadIdx.x;
    // XCD co-location swizzle: all 4 quarters of a batch on one XCD.
    const int xcd     = blockIdx.x & 7;
    const int slot_   = blockIdx.x >> 3;
    const int bt      = xcd * 4 + (slot_ & 3);   // batch
    const int quarter = slot_ >> 2;              // which quarter of the signal
    const int lane    = t & 63;
    const int wave    = t >> 6;
    const int lf      = wave >> 1;               // local frame 0..5
    const int frame   = quarter * 6 + lf;        // global frame

    // ---------------- coefficient init (threads 0..383) ----------------
    if (t < NB * NF) {
        const int f  = t / NF;
        const int fr = t % NF;
        const float* P = params + (size_t)bt * 50 * NF;
        const float fn = P[(3 * f + 0) * NF + fr];
        const float gn = P[(3 * f + 1) * NF + fr];
        const float qn = P[(3 * f + 2) * NF + fr];

        float Q = __expf(-0.69314718f + qn * 3.4657359f);
        Q = clampf(Q, 0.1f, 100.0f);

        float lo, hi;
        int type;                        // 0 hp, 1 lp, 2 peak, 3 lowshelf, 4 highshelf
        if      (f == 0)  { lo = 20.0f;   hi = 500.0f;   type = 0; }
        else if (f == 15) { lo = 5000.0f; hi = 20000.0f; type = 1; }
        else if (f == 1)  { lo = 50.0f;   hi = 16000.0f; type = 3; }
        else if (f == 14) { lo = 50.0f;   hi = 16000.0f; type = 4; }
        else              { lo = 100.0f;  hi = 15000.0f; type = 2; }

        const float fc = __expf(__logf(lo) + fn * (__logf(hi) - __logf(lo)));
        float g_ = __tanf((float)M_PI * fc / 96000.0f);   // angle <= 0.655 rad
        g_ = clampf(g_, 1e-6f, 100.0f);
        const float gdb = -24.0f + 48.0f * gn;

        float a1, a2, a3, m0, m1, m2;
        if (type == 0 || type == 1) {
            const float k = 1.0f / Q;
            a1 = 1.0f / (1.0f + g_ * (g_ + k)); a2 = g_ * a1; a3 = g_ * a2;
            if (type == 0) { m0 = 1.0f; m1 = -k;   m2 = -1.0f; }
            else           { m0 = 0.0f; m1 = 0.0f; m2 = 1.0f;  }
        } else if (type == 2) {
            const float A = __expf(gdb * (2.30258509f / 40.0f));
            const float k = (gdb >= 0.0f) ? 1.0f / (Q * A) : A / Q;
            a1 = 1.0f / (1.0f + g_ * (g_ + k)); a2 = g_ * a1; a3 = g_ * a2;
            m0 = 1.0f; m1 = k * (A * A - 1.0f); m2 = 0.0f;
        } else {
            const float A  = __expf(gdb * (2.30258509f / 40.0f));
            const float sA = sqrtf(A);
            const float k  = 1.0f / Q;
            float gs;
            if (type == 3) gs = (gdb >= 0.0f) ? g_ / sA : g_ * sA;
            else           gs = (gdb >= 0.0f) ? g_ * sA : g_ / sA;
            a1 = 1.0f / (1.0f + gs * (gs + k)); a2 = gs * a1; a3 = gs * a2;
            if (type == 3) { m0 = 1.0f;  m1 = k * (A - 1.0f);      m2 = A * A - 1.0f; }
            else           { m0 = A * A; m1 = k * (1.0f - A) * A;  m2 = 1.0f - A * A; }
        }

        // affine per-sample form: s' = T s + b*x ; y = c0*s1 + c1*s2 + c2*x
        const float q2  = a2 * a2 + a3;
        const float t00 = 2.0f * a1 - 1.0f;
        const float t01 = -2.0f * a2;
        const float t10 = 2.0f * a1 * a2;
        const float t11 = 1.0f - 2.0f * q2;
        const float b0  = 2.0f * a2;
        const float b1  = 2.0f * q2;
        const float c0  = a1 * (m1 + m2 * a2);
        const float c1  = m2 * (1.0f - q2) - m1 * a2;
        const float c2  = m0 + m1 * a2 + m2 * q2;

        const int lfr   = fr - quarter * 6;
        const bool loc  = (lfr >= 0 && lfr < 6);

        if (loc) {
            float* d = sc[f][lfr];
            d[0] = t00; d[1] = t01; d[2] = t10; d[3] = t11;
            d[4] = b0;  d[5] = b1;  d[6] = c0;  d[7] = c1;
            d[8] = c2;  d[9] = 0.0f; d[10] = 0.0f; d[11] = 0.0f;
        }

        // T^16 by 4 squarings, then store (T^16)^(2^j) j=0..5, then T^1024, T^2048
        float u00 = t00, u01 = t01, u10 = t10, u11 = t11;
        #pragma unroll
        for (int i = 0; i < 4; i++) {
            const float n00 = u00 * u00 + u01 * u10;
            const float n01 = u00 * u01 + u01 * u11;
            const float n10 = u10 * u00 + u11 * u10;
            const float n11 = u10 * u01 + u11 * u11;
            u00 = n00; u01 = n01; u10 = n10; u11 = n11;
        }
        #pragma unroll
        for (int j = 0; j < 6; j++) {
            if (loc) spow[f][lfr][j] = make_float4(u00, u01, u10, u11);
            const float n00 = u00 * u00 + u01 * u10;
            const float n01 = u00 * u01 + u01 * u11;
            const float n10 = u10 * u00 + u11 * u10;
            const float n11 = u10 * u01 + u11 * u11;
            u00 = n00; u01 = n01; u10 = n10; u11 = n11;
        }
        // u = T^1024 now
        if (loc) sMw[f][lfr] = make_float4(u00, u01, u10, u11);
        {
            const float n00 = u00 * u00 + u01 * u10;
            const float n01 = u00 * u01 + u01 * u11;
            const float n10 = u10 * u00 + u11 * u10;
            const float n11 = u10 * u01 + u11 * u11;
            sT2048[f][fr] = make_float4(n00, n01, n10, n11);
        }
    }
    if (t >= 384 && t < 384 + 2 * NF) {
        const int idx = t - 384;
        const int which = idx / NF;     // 0 = in gain (row 48), 1 = out gain (row 49)
        const int fr    = idx % NF;
        const float* P = params + (size_t)bt * 50 * NF;
        const float p  = P[(48 + which) * NF + fr];
        const float db = -60.0f + 60.0f * p;
        sgain[which][fr] = __expf(db * (2.30258509f / 20.0f));
    }
    if (t < NB) sflag[t] = 0u;
    __syncthreads();

    // ------- prefix assembly (threads 0..15, one per stage) -------
    if (t < NB) {
        const int f = t;
        // exclusive wave prefixes P_w over local frames (Q = running product)
        float q00 = 1.0f, q01 = 0.0f, q10 = 0.0f, q11 = 1.0f;
        #pragma unroll
        for (int k = 0; k < 6; k++) {
            sPm[f][2 * k][0] = make_float4(q00, q01, q10, q11);
            const float4 mw = sMw[f][k];
            sPm[f][2 * k + 1][0] = make_float4(
                mw.x * q00 + mw.y * q10, mw.x * q01 + mw.y * q11,
                mw.z * q00 + mw.w * q10, mw.z * q01 + mw.w * q11);
            const float4 g = sT2048[f][quarter * 6 + k];
            const float n00 = g.x * q00 + g.y * q10;
            const float n01 = g.x * q01 + g.y * q11;
            const float n10 = g.z * q00 + g.w * q10;
            const float n11 = g.z * q01 + g.w * q11;
            q00 = n00; q01 = n01; q10 = n10; q11 = n11;
        }
        // pred-quarter fold matrices: W_{q-1}=I ; W_k = W_{k+1} * B_{k+1}
        if (quarter > 0) {
            float r00 = 1.0f, r01 = 0.0f, r10 = 0.0f, r11 = 1.0f;
            for (int k = quarter - 1; k >= 0; k--) {
                sWm[f][k] = make_float4(r00, r01, r10, r11);
                if (k > 0) {
                    float b00 = 1.0f, b01 = 0.0f, b10 = 0.0f, b11 = 1.0f;
                    #pragma unroll
                    for (int m = 0; m < 6; m++) {
                        const float4 g = sT2048[f][6 * k + m];
                        const float n00 = g.x * b00 + g.y * b10;
                        const float n01 = g.x * b01 + g.y * b11;
                        const float n10 = g.z * b00 + g.w * b10;
                        const float n11 = g.z * b01 + g.w * b11;
                        b00 = n00; b01 = n01; b10 = n10; b11 = n11;
                    }
                    const float n00 = r00 * b00 + r01 * b10;
                    const float n01 = r00 * b01 + r01 * b11;
                    const float n10 = r10 * b00 + r11 * b10;
                    const float n11 = r10 * b01 + r11 * b11;
                    r00 = n00; r01 = n01; r10 = n10; r11 = n11;
                }
            }
        }
    }
    __syncthreads();

    // ---------------- load chunk (with input gain) ----------------
    FOREACH_S(DECL_S)
    {
        const float ing = sgain[0][frame];
        const float* base = audio + (size_t)bt * S
                          + (size_t)(quarter * NCH + t) * CHUNK;
        float4 q;
        q = *(const float4*)(base +  0); s00 = q.x*ing; s01 = q.y*ing; s02 = q.z*ing; s03 = q.w*ing;
        q = *(const float4*)(base +  4); s04 = q.x*ing; s05 = q.y*ing; s06 = q.z*ing; s07 = q.w*ing;
        q = *(const float4*)(base +  8); s08 = q.x*ing; s09 = q.y*ing; s10 = q.z*ing; s11 = q.w*ing;
        q = *(const float4*)(base + 12); s12 = q.x*ing; s13 = q.y*ing; s14 = q.z*ing; s15 = q.w*ing;
    }

    // ---------------- prologue: PhaseA(stage 0) ----------------
    float ja = 0.0f, jb = 0.0f;
    float u00, u01, u10, u11, e0, e1;
    {
        const float4 q0 = *(const float4*)&sc[0][lf][0];
        const float2 q1 = *(const float2*)&sc[0][lf][4];
        u00 = q0.x; u01 = q0.y; u10 = q0.z; u11 = q0.w;
        e0 = q1.x; e1 = q1.y;
        FOREACH_S(STEPA)
    }

    // ---------------- 16 rounds (fused C_f + A_{f+1}) ----------------
    #pragma unroll 1
    for (int f = 0; f < NB; f++) {
        // constants-only Kogge-Stone with precomputed powers
        float Ac0 = ja, Ac1 = jb;
        #pragma unroll
        for (int j = 0; j < 6; j++) {
            const float4 mm = spow[f][lf][j];
            const int d = 1 << j;
            const float lc0 = __shfl_up(Ac0, d);
            const float lc1 = __shfl_up(Ac1, d);
            if (lane >= d) {
                const float n0 = fmaf(mm.x, lc0, fmaf(mm.y, lc1, Ac0));
                const float n1 = fmaf(mm.z, lc0, fmaf(mm.w, lc1, Ac1));
                Ac0 = n0; Ac1 = n1;
            }
        }
        // Ac at lane 63 = wave aggregate constant

        const int buf = f & 1;
        if (lane == 63) sagg[buf][wave] = make_float2(Ac0, Ac1);
        __syncthreads();   // the ONE barrier per round

        const unsigned int tag = (unsigned int)(f + 1);
        unsigned int* stagebase = ws + ((size_t)(bt * NB + f) * NBLK) * 8;

        if (wave == 0) {
            // predicated 12-step constants fold (precomputed M_w from LDS)
            float Pc0 = 0.0f, Pc1 = 0.0f;
            #pragma unroll
            for (int j = 0; j < NWAVE; j++) {
                const float2 a = sagg[buf][j];
                const float4 mw = sMw[f][j >> 1];
                if (lane > j) {
                    const float n0 = fmaf(mw.x, Pc0, fmaf(mw.y, Pc1, a.x));
                    const float n1 = fmaf(mw.z, Pc0, fmaf(mw.w, Pc1, a.y));
                    Pc0 = n0; Pc1 = n1;
                }
            }

            // publish block-own inclusive constant (lane 12) ASAP
            if (quarter < NBLK - 1 && lane == NWAVE) {
                unsigned int* slot = stagebase + quarter * 8;
                float* dp = (float*)(slot + 1);
                __hip_atomic_store(&dp[0], Pc0, __ATOMIC_RELAXED, __HIP_MEMORY_SCOPE_AGENT);
                __hip_atomic_store(&dp[1], Pc1, __ATOMIC_RELAXED, __HIP_MEMORY_SCOPE_AGENT);
                __hip_atomic_store(slot, tag, __ATOMIC_RELEASE, __HIP_MEMORY_SCOPE_AGENT);
            }

            // block incoming state: PARALLEL polls + precomputed-W fold
            float S0x = 0.0f, S0y = 0.0f;
            if (quarter > 0) {
                float ux = 0.0f, uy = 0.0f;
                if (lane < quarter) {
                    unsigned int* slot = stagebase + lane * 8;
                    while (__hip_atomic_load(slot, __ATOMIC_ACQUIRE, __HIP_MEMORY_SCOPE_AGENT) != tag) {
                        __builtin_amdgcn_s_sleep(1);
                    }
                    const float* dp = (const float*)(slot + 1);
                    const float cx = __hip_atomic_load(&dp[0], __ATOMIC_RELAXED, __HIP_MEMORY_SCOPE_AGENT);
                    const float cy = __hip_atomic_load(&dp[1], __ATOMIC_RELAXED, __HIP_MEMORY_SCOPE_AGENT);
                    const float4 w = sWm[f][lane];
                    ux = fmaf(w.x, cx, w.y * cy);
                    uy = fmaf(w.z, cx, w.w * cy);
                }
                S0x = __shfl(ux, 0);
                S0y = __shfl(uy, 0);
                if (quarter > 1) { S0x += __shfl(ux, 1); S0y += __shfl(uy, 1); }
                if (quarter > 2) { S0x += __shfl(ux, 2); S0y += __shfl(uy, 2); }
            }

            // per-wave incoming state v = P_w * S0 + Pc_w ; lanes 0..11
            if (lane < NWAVE) {
                const float4 pm = sPm[f][lane][0];
                sv[lane] = make_float2(
                    fmaf(pm.x, S0x, fmaf(pm.y, S0y, Pc0)),
                    fmaf(pm.z, S0x, fmaf(pm.w, S0y, Pc1)));
            }
            if (lane == 0) {
                __hip_atomic_store(&sflag[f], tag, __ATOMIC_RELEASE,
                                   __HIP_MEMORY_SCOPE_WORKGROUP);
            }
        } else {
            // ready-flag spin replaces bar2
            while (__hip_atomic_load(&sflag[f], __ATOMIC_ACQUIRE,
                                     __HIP_MEMORY_SCOPE_WORKGROUP) != tag)
                __builtin_amdgcn_s_sleep(1);
        }

        const float2 v = sv[wave];

        // lane-exclusive constants
        float ce0 = __shfl_up(Ac0, 1);
        float ce1 = __shfl_up(Ac1, 1);
        if (lane == 0) { ce0 = 0.0f; ce1 = 0.0f; }

        // distribute: ic = M^lane * v + ce (binexp with precomputed powers)
        float w0 = v.x, w1 = v.y;
        #pragma unroll
        for (int b = 0; b < 6; b++) {
            const float4 pm = spow[f][lf][b];
            if (lane & (1 << b)) {
                const float nw0 = fmaf(pm.x, w0, pm.y * w1);
                const float nw1 = fmaf(pm.z, w0, pm.w * w1);
                w0 = nw0; w1 = nw1;
            }
        }
        float ic1 = w0 + ce0;
        float ic2 = w1 + ce1;

        // current-stage coeffs: T,b from u/e (rolled from prev round), c fresh
        const float t00 = u00, t01 = u01, t10 = u10, t11 = u11;
        const float b0v = e0, b1v = e1;
        const float c0  = sc[f][lf][6];
        const float c1  = sc[f][lf][7];
        const float c2v = sc[f][lf][8];

        if (f < NB - 1) {
            // load next stage's T,b for the fused A-part
            const float4 qn = *(const float4*)&sc[f + 1][lf][0];
            const float2 qb = *(const float2*)&sc[f + 1][lf][4];
            u00 = qn.x; u01 = qn.y; u10 = qn.z; u11 = qn.w;
            e0 = qb.x; e1 = qb.y;
            ja = 0.0f; jb = 0.0f;
            FOREACH_S(STEPF)
        } else {
            FOREACH_S(STEPC)
        }
    }

    // ---------------- store (with output gain) ----------------
    {
        const float og = sgain[1][frame];
        float* base = out + (size_t)bt * S + (size_t)(quarter * NCH + t) * CHUNK;
        float4 q;
        q.x = s00*og; q.y = s01*og; q.z = s02*og; q.w = s03*og; *(float4*)(base +  0) = q;
        q.x = s04*og; q.y = s05*og; q.z = s06*og; q.w = s07*og; *(float4*)(base +  4) = q;
        q.x = s08*og; q.y = s09*og; q.z = s10*og; q.w = s11*og; *(float4*)(base +  8) = q;
        q.x = s12*og; q.y = s13*og; q.z = s14*og; q.w = s15*og; *(float4*)(base + 12) = q;
    }
}

extern "C" void kernel_launch(void* const* d_in, const int* in_sizes, int n_in,
                              void* d_out, int out_size, void* d_ws, size_t ws_size,
                              hipStream_t stream)
{
    const float* audio  = (const float*)d_in[0];
    const float* params = (const float*)d_in[1];
    float* out = (float*)d_out;
    unsigned int* ws = (unsigned int*)d_ws;
    biquad_chain_kernel<<<NBLK * NBATCH, NCH, 0, stream>>>(audio, params, out, ws);
}

// Round 10
// 130.637 us; speedup vs baseline: 1.0383x; 1.0002x over previous
//
#include <hip/hip_runtime.h>
#include <math.h>

#define NBATCH 32
#define S      49152
#define NF     24          // frames (2048 samples each)
#define NB     16          // biquads
#define NBLK   4           // blocks per batch (R9-proven best)
#define CHUNK  16          // samples per thread (R9-proven; 32 spills)
#define NCH    768         // threads per block
#define NWAVE  12          // waves per block
// R19 = R16 (best clean, 71.5us) with the cross-lane DS chain replaced by DPP.
// Evidence R18: moving KS matrices from registers to LDS (+12 ds_reads on the
// lgkm path) cost +8us -> the round's serial core is the ds_bpermute shfl
// chain (6 deps x ~120cy), not FMA issue. R19: in-row scan via row_shr DPP
// (VALU speed), cross-row via row_bcast15/31 with per-lane compose matrices
// M*(M16^b4)*M^(lane&15) built from register powers (rocPRIM gfx9 scan
// pattern, generalized to 2x2 affine). Distribute reuses D/M16/M32 (3
// matvecs). The single remaining shfl_up(ce) issues pre-barrier so its
// latency hides under convergence. Fused STEPF loop kept from R18 (numerics
// proven). Everything else R16 verbatim.
// Health: WRITE ~7.1MB, VGPR <= 84, bank conflicts << 123k.

__device__ __forceinline__ float clampf(float x, float lo, float hi) {
    return fminf(fmaxf(x, lo), hi);
}

template<int CTRL, int RMASK>
__device__ __forceinline__ float dppf(float x) {
    return __int_as_float(__builtin_amdgcn_update_dpp(
        0, __float_as_int(x), CTRL, RMASK, 0xf, true));
}

// 16 named scalar signal registers (SSA-guaranteed; arrays spill).
#define FOREACH_S(OP) \
    OP(s00) OP(s01) OP(s02) OP(s03) OP(s04) OP(s05) OP(s06) OP(s07) \
    OP(s08) OP(s09) OP(s10) OP(s11) OP(s12) OP(s13) OP(s14) OP(s15)

#define DECL_S(x) float x;

// Prologue Phase A step (stage 0): zero-state accumulation into ja/jb.
#define STEPA(x) { \
    const float n1_ = fmaf(tc00, ja, fmaf(tc01, jb, bc0 * (x))); \
    const float n2_ = fmaf(tc10, ja, fmaf(tc11, jb, bc1 * (x))); \
    ja = n1_; jb = n2_; }

// Final round: output + state only.
#define STEPC(x) { \
    const float y_  = fmaf(c0, ic1, fmaf(c1, ic2, c2v * (x))); \
    const float n1_ = fmaf(tc00, ic1, fmaf(tc01, ic2, bc0 * (x))); \
    const float n2_ = fmaf(tc10, ic1, fmaf(tc11, ic2, bc1 * (x))); \
    (x) = y_; ic1 = n1_; ic2 = n2_; }

// Fused: stage f output + state, AND stage f+1 zero-state accumulation.
#define STEPF(x) { \
    const float y_  = fmaf(c0, ic1, fmaf(c1, ic2, c2v * (x))); \
    const float n1_ = fmaf(tc00, ic1, fmaf(tc01, ic2, bc0 * (x))); \
    const float n2_ = fmaf(tc10, ic1, fmaf(tc11, ic2, bc1 * (x))); \
    (x) = y_; ic1 = n1_; ic2 = n2_; \
    const float m1_ = fmaf(nt00, ja, fmaf(nt01, jb, nb0 * y_)); \
    const float m2_ = fmaf(nt10, ja, fmaf(nt11, jb, nb1 * y_)); \
    ja = m1_; jb = m2_; }

// DPP scan step with distance DD (in-row), compose matrix P=M^DD, plus
// predicated D accumulation and P squaring (all register dataflow).
#define KSTEP(DD, CTRL) { \
    const float lc0 = dppf<CTRL, 0xf>(Ac0); \
    const float lc1 = dppf<CTRL, 0xf>(Ac1); \
    if (l4 >= DD) { \
        const float n0 = fmaf(p00, lc0, fmaf(p01, lc1, Ac0)); \
        const float n1 = fmaf(p10, lc0, fmaf(p11, lc1, Ac1)); \
        Ac0 = n0; Ac1 = n1; } \
    if (l4 & DD) { \
        const float nd00 = p00 * d00 + p01 * d10; \
        const float nd01 = p00 * d01 + p01 * d11; \
        const float nd10 = p10 * d00 + p11 * d10; \
        const float nd11 = p10 * d01 + p11 * d11; \
        d00 = nd00; d01 = nd01; d10 = nd10; d11 = nd11; } \
    { const float n00 = p00 * p00 + p01 * p10; \
      const float n01 = p00 * p01 + p01 * p11; \
      const float n10 = p10 * p00 + p11 * p10; \
      const float n11 = p10 * p01 + p11 * p11; \
      p00 = n00; p01 = n01; p10 = n10; p11 = n11; } }

__global__ __launch_bounds__(NCH, 3)
void biquad_chain_kernel(const float* __restrict__ audio,
                         const float* __restrict__ params,
                         float* __restrict__ out,
                         unsigned int* __restrict__ ws)
{
    __shared__ __align__(16) float sc[NB][NF][16];  // affine(9) + T^16(4)
    __shared__ float4 sMw[NB][6];         // T^1024 per local frame
    __shared__ float4 sPm[NB][NWAVE];     // exclusive wave-prefix P_w
    __shared__ float4 sWm[NB][3];         // pred-quarter fold matrices W_k
    __shared__ float4 sT2048[NB][NF];     // frame aggregates (init/prefix only)
    __shared__ float  sgain[2][NF];       // [0]=in gain, [1]=out gain
    __shared__ float2 sagg[2][NWAVE];     // runtime wave constants (dbuf)
    __shared__ float2 sv[NWAVE];          // per-wave incoming state
    __shared__ unsigned int sflag[NB];    // per-stage sv-ready flag

    const int t       = threadIdx.x;
    // XCD co-location swizzle: all 4 quarters of a batch on one XCD.
    const int xcd     = blockIdx.x & 7;
    const int slot_   = blockIdx.x >> 3;
    const int bt      = xcd * 4 + (slot_ & 3);   // batch
    const int quarter = slot_ >> 2;              // which quarter of the signal
    const int lane    = t & 63;
    const int wave    = t >> 6;
    const int frame   = quarter * 6 + (wave >> 1);  // 2 waves per 2048-frame

    // ---------------- coefficient init (threads 0..383) ----------------
    if (t < NB * NF) {
        const int f  = t / NF;
        const int fr = t % NF;
        const float* P = params + (size_t)bt * 50 * NF;
        const float fn = P[(3 * f + 0) * NF + fr];
        const float gn = P[(3 * f + 1) * NF + fr];
        const float qn = P[(3 * f + 2) * NF + fr];

        float Q = __expf(-0.69314718f + qn * 3.4657359f);
        Q = clampf(Q, 0.1f, 100.0f);

        float lo, hi;
        int type;                        // 0 hp, 1 lp, 2 peak, 3 lowshelf, 4 highshelf
        if      (f == 0)  { lo = 20.0f;   hi = 500.0f;   type = 0; }
        else if (f == 15) { lo = 5000.0f; hi = 20000.0f; type = 1; }
        else if (f == 1)  { lo = 50.0f;   hi = 16000.0f; type = 3; }
        else if (f == 14) { lo = 50.0f;   hi = 16000.0f; type = 4; }
        else              { lo = 100.0f;  hi = 15000.0f; type = 2; }

        const float fc = __expf(__logf(lo) + fn * (__logf(hi) - __logf(lo)));
        float g_ = __tanf((float)M_PI * fc / 96000.0f);   // angle <= 0.655 rad
        g_ = clampf(g_, 1e-6f, 100.0f);
        const float gdb = -24.0f + 48.0f * gn;

        float a1, a2, a3, m0, m1, m2;
        if (type == 0 || type == 1) {
            const float k = 1.0f / Q;
            a1 = 1.0f / (1.0f + g_ * (g_ + k)); a2 = g_ * a1; a3 = g_ * a2;
            if (type == 0) { m0 = 1.0f; m1 = -k;   m2 = -1.0f; }
            else           { m0 = 0.0f; m1 = 0.0f; m2 = 1.0f;  }
        } else if (type == 2) {
            const float A = __expf(gdb * (2.30258509f / 40.0f));
            const float k = (gdb >= 0.0f) ? 1.0f / (Q * A) : A / Q;
            a1 = 1.0f / (1.0f + g_ * (g_ + k)); a2 = g_ * a1; a3 = g_ * a2;
            m0 = 1.0f; m1 = k * (A * A - 1.0f); m2 = 0.0f;
        } else {
            const float A  = __expf(gdb * (2.30258509f / 40.0f));
            const float sA = sqrtf(A);
            const float k  = 1.0f / Q;
            float gs;
            if (type == 3) gs = (gdb >= 0.0f) ? g_ / sA : g_ * sA;
            else           gs = (gdb >= 0.0f) ? g_ * sA : g_ / sA;
            a1 = 1.0f / (1.0f + gs * (gs + k)); a2 = gs * a1; a3 = gs * a2;
            if (type == 3) { m0 = 1.0f;  m1 = k * (A - 1.0f);      m2 = A * A - 1.0f; }
            else           { m0 = A * A; m1 = k * (1.0f - A) * A;  m2 = 1.0f - A * A; }
        }

        // affine per-sample form: s' = T s + b*x ; y = c0*s1 + c1*s2 + c2*x
        const float q2  = a2 * a2 + a3;
        const float t00 = 2.0f * a1 - 1.0f;
        const float t01 = -2.0f * a2;
        const float t10 = 2.0f * a1 * a2;
        const float t11 = 1.0f - 2.0f * q2;
        const float b0  = 2.0f * a2;
        const float b1  = 2.0f * q2;
        const float c0  = a1 * (m1 + m2 * a2);
        const float c1  = m2 * (1.0f - q2) - m1 * a2;
        const float c2  = m0 + m1 * a2 + m2 * q2;

        // T^16 by 4 squarings
        float u00 = t00, u01 = t01, u10 = t10, u11 = t11;
        #pragma unroll
        for (int i = 0; i < 4; i++) {
            const float n00 = u00 * u00 + u01 * u10;
            const float n01 = u00 * u01 + u01 * u11;
            const float n10 = u10 * u00 + u11 * u10;
            const float n11 = u10 * u01 + u11 * u11;
            u00 = n00; u01 = n01; u10 = n10; u11 = n11;
        }
        sc[f][fr][0] = t00; sc[f][fr][1] = t01; sc[f][fr][2] = t10; sc[f][fr][3] = t11;
        sc[f][fr][4] = b0;  sc[f][fr][5] = b1;  sc[f][fr][6] = c0;  sc[f][fr][7] = c1;
        sc[f][fr][8] = c2;  sc[f][fr][9] = u00; sc[f][fr][10] = u01; sc[f][fr][11] = u10;
        sc[f][fr][12] = u11;

        // continue squaring: T^16 -> T^1024 (6 more squarings)
        #pragma unroll
        for (int i = 0; i < 6; i++) {
            const float n00 = u00 * u00 + u01 * u10;
            const float n01 = u00 * u01 + u01 * u11;
            const float n10 = u10 * u00 + u11 * u10;
            const float n11 = u10 * u01 + u11 * u11;
            u00 = n00; u01 = n01; u10 = n10; u11 = n11;
        }
        const int lfr = fr - quarter * 6;
        if (lfr >= 0 && lfr < 6) {
            sMw[f][lfr] = make_float4(u00, u01, u10, u11);
        }
        // one more squaring: T^2048 (frame aggregate, ALL frames)
        {
            const float n00 = u00 * u00 + u01 * u10;
            const float n01 = u00 * u01 + u01 * u11;
            const float n10 = u10 * u00 + u11 * u10;
            const float n11 = u10 * u01 + u11 * u11;
            sT2048[f][fr] = make_float4(n00, n01, n10, n11);
        }
    }
    if (t >= 384 && t < 384 + 2 * NF) {
        const int idx = t - 384;
        const int which = idx / NF;     // 0 = in gain (row 48), 1 = out gain (row 49)
        const int fr    = idx % NF;
        const float* P = params + (size_t)bt * 50 * NF;
        const float p  = P[(48 + which) * NF + fr];
        const float db = -60.0f + 60.0f * p;
        sgain[which][fr] = __expf(db * (2.30258509f / 20.0f));
    }
    if (t < NB) sflag[t] = 0u;
    __syncthreads();

    // ------- prefix assembly (threads 0..15, one per stage) -------
    if (t < NB) {
        const int f = t;
        // exclusive wave prefixes P_w over local frames (Q = running product)
        float q00 = 1.0f, q01 = 0.0f, q10 = 0.0f, q11 = 1.0f;
        #pragma unroll
        for (int k = 0; k < 6; k++) {
            sPm[f][2 * k] = make_float4(q00, q01, q10, q11);
            const float4 mw = sMw[f][k];
            sPm[f][2 * k + 1] = make_float4(
                mw.x * q00 + mw.y * q10, mw.x * q01 + mw.y * q11,
                mw.z * q00 + mw.w * q10, mw.z * q01 + mw.w * q11);
            const float4 g = sT2048[f][quarter * 6 + k];
            const float n00 = g.x * q00 + g.y * q10;
            const float n01 = g.x * q01 + g.y * q11;
            const float n10 = g.z * q00 + g.w * q10;
            const float n11 = g.z * q01 + g.w * q11;
            q00 = n00; q01 = n01; q10 = n10; q11 = n11;
        }
        // pred-quarter fold matrices: W_{q-1}=I ; W_k = W_{k+1} * B_{k+1}
        if (quarter > 0) {
            float r00 = 1.0f, r01 = 0.0f, r10 = 0.0f, r11 = 1.0f;
            for (int k = quarter - 1; k >= 0; k--) {
                sWm[f][k] = make_float4(r00, r01, r10, r11);
                if (k > 0) {
                    float b00 = 1.0f, b01 = 0.0f, b10 = 0.0f, b11 = 1.0f;
                    #pragma unroll
                    for (int m = 0; m < 6; m++) {
                        const float4 g = sT2048[f][6 * k + m];
                        const float n00 = g.x * b00 + g.y * b10;
                        const float n01 = g.x * b01 + g.y * b11;
                        const float n10 = g.z * b00 + g.w * b10;
                        const float n11 = g.z * b01 + g.w * b11;
                        b00 = n00; b01 = n01; b10 = n10; b11 = n11;
                    }
                    const float n00 = r00 * b00 + r01 * b10;
                    const float n01 = r00 * b01 + r01 * b11;
                    const float n10 = r10 * b00 + r11 * b10;
                    const float n11 = r10 * b01 + r11 * b11;
                    r00 = n00; r01 = n01; r10 = n10; r11 = n11;
                }
            }
        }
    }
    __syncthreads();

    // ---------------- load chunk (with input gain) ----------------
    FOREACH_S(DECL_S)
    {
        const float ing = sgain[0][frame];
        const float* base = audio + (size_t)bt * S
                          + (size_t)(quarter * NCH + t) * CHUNK;
        float4 q;
        q = *(const float4*)(base +  0); s00 = q.x*ing; s01 = q.y*ing; s02 = q.z*ing; s03 = q.w*ing;
        q = *(const float4*)(base +  4); s04 = q.x*ing; s05 = q.y*ing; s06 = q.z*ing; s07 = q.w*ing;
        q = *(const float4*)(base +  8); s08 = q.x*ing; s09 = q.y*ing; s10 = q.z*ing; s11 = q.w*ing;
        q = *(const float4*)(base + 12); s12 = q.x*ing; s13 = q.y*ing; s14 = q.z*ing; s15 = q.w*ing;
    }

    // ---------------- prologue: PhaseA(stage 0) ----------------
    float ja = 0.0f, jb = 0.0f;
    float tc00, tc01, tc10, tc11, bc0, bc1;
    {
        const float4 q0 = *(const float4*)&sc[0][frame][0];
        const float2 q1 = *(const float2*)&sc[0][frame][4];
        tc00 = q0.x; tc01 = q0.y; tc10 = q0.z; tc11 = q0.w;
        bc0 = q1.x; bc1 = q1.y;
        FOREACH_S(STEPA)
    }

    const int l4 = lane & 15;

    // ---------------- 16 rounds (fused C_f + A_{f+1}) ----------------
    #pragma unroll 1
    for (int f = 0; f < NB; f++) {
        const float4 qm = *(const float4*)&sc[f][frame][8];  // c2 M00 M01 M10
        const float  M11v = sc[f][frame][12];
        const float c2v = qm.x;
        const float m00 = qm.y, m01 = qm.z, m10 = qm.w, m11 = M11v;

        // ---- DPP affine scan (in-row row_shr + cross-row row_bcast) ----
        float Ac0 = ja, Ac1 = jb;
        float p00 = m00, p01 = m01, p10 = m10, p11 = m11;    // P = M^d
        float d00 = 1.0f, d01 = 0.0f, d10 = 0.0f, d11 = 1.0f; // D = M^(lane&15)
        KSTEP(1, 0x111)
        KSTEP(2, 0x112)
        KSTEP(4, 0x114)
        KSTEP(8, 0x118)
        // P = M^16 now
        // cross-row 1: rows 1,3 compose with lane 15/47 inclusive
        {
            const float cc0 = dppf<0x142, 0xa>(Ac0);
            const float cc1 = dppf<0x142, 0xa>(Ac1);
            if (lane & 16) {
                const float t0 = fmaf(d00, cc0, d01 * cc1);
                const float t1 = fmaf(d10, cc0, d11 * cc1);
                Ac0 = fmaf(m00, t0, fmaf(m01, t1, Ac0));
                Ac1 = fmaf(m10, t0, fmaf(m11, t1, Ac1));
            }
        }
        // save G = M^16, advance P to M^32
        const float g00 = p00, g01 = p01, g10 = p10, g11 = p11;
        {
            const float n00 = p00 * p00 + p01 * p10;
            const float n01 = p00 * p01 + p01 * p11;
            const float n10 = p10 * p00 + p11 * p10;
            const float n11 = p10 * p01 + p11 * p11;
            p00 = n00; p01 = n01; p10 = n10; p11 = n11;
        }
        // cross-row 2: rows 2,3 compose with lane 31 inclusive
        {
            const float cc0 = dppf<0x143, 0xc>(Ac0);
            const float cc1 = dppf<0x143, 0xc>(Ac1);
            if (lane & 32) {
                float t0 = fmaf(d00, cc0, d01 * cc1);
                float t1 = fmaf(d10, cc0, d11 * cc1);
                if (lane & 16) {
                    const float w0 = fmaf(g00, t0, g01 * t1);
                    const float w1 = fmaf(g10, t0, g11 * t1);
                    t0 = w0; t1 = w1;
                }
                Ac0 = fmaf(m00, t0, fmaf(m01, t1, Ac0));
                Ac1 = fmaf(m10, t0, fmaf(m11, t1, Ac1));
            }
        }
        // Ac = inclusive prefix constant; lane 63 = wave aggregate

        const int buf = f & 1;
        if (lane == 63) sagg[buf][wave] = make_float2(Ac0, Ac1);

        // ce = exclusive (shfl_up 1) -- issue NOW; latency hides under barrier
        float ce0 = __shfl_up(Ac0, 1);
        float ce1 = __shfl_up(Ac1, 1);
        if (lane == 0) { ce0 = 0.0f; ce1 = 0.0f; }

        __syncthreads();   // the ONE barrier per round (sagg[buf] ready)

        const unsigned int tag = (unsigned int)(f + 1);
        unsigned int* stagebase = ws + ((size_t)(bt * NB + f) * NBLK) * 8;

        if (wave == 0) {
            // predicated 12-step constants fold (precomputed M_w from LDS)
            float Pc0 = 0.0f, Pc1 = 0.0f;
            #pragma unroll
            for (int j = 0; j < NWAVE; j++) {
                const float2 a = sagg[buf][j];
                const float4 mw = sMw[f][j >> 1];
                if (lane > j) {
                    const float n0 = fmaf(mw.x, Pc0, fmaf(mw.y, Pc1, a.x));
                    const float n1 = fmaf(mw.z, Pc0, fmaf(mw.w, Pc1, a.y));
                    Pc0 = n0; Pc1 = n1;
                }
            }

            // publish block-own inclusive constant (lane 12) ASAP
            if (quarter < NBLK - 1 && lane == NWAVE) {
                unsigned int* slot = stagebase + quarter * 8;
                float* dp = (float*)(slot + 1);
                __hip_atomic_store(&dp[0], Pc0, __ATOMIC_RELAXED, __HIP_MEMORY_SCOPE_AGENT);
                __hip_atomic_store(&dp[1], Pc1, __ATOMIC_RELAXED, __HIP_MEMORY_SCOPE_AGENT);
                __hip_atomic_store(slot, tag, __ATOMIC_RELEASE, __HIP_MEMORY_SCOPE_AGENT);
            }

            // block incoming state: PARALLEL polls + precomputed-W fold
            float S0x = 0.0f, S0y = 0.0f;
            if (quarter > 0) {
                float ux = 0.0f, uy = 0.0f;
                if (lane < quarter) {
                    unsigned int* slot = stagebase + lane * 8;
                    while (__hip_atomic_load(slot, __ATOMIC_ACQUIRE, __HIP_MEMORY_SCOPE_AGENT) != tag) {
                        __builtin_amdgcn_s_sleep(1);
                    }
                    const float* dp = (const float*)(slot + 1);
                    const float cx = __hip_atomic_load(&dp[0], __ATOMIC_RELAXED, __HIP_MEMORY_SCOPE_AGENT);
                    const float cy = __hip_atomic_load(&dp[1], __ATOMIC_RELAXED, __HIP_MEMORY_SCOPE_AGENT);
                    const float4 w = sWm[f][lane];
                    ux = fmaf(w.x, cx, w.y * cy);
                    uy = fmaf(w.z, cx, w.w * cy);
                }
                S0x = __shfl(ux, 0);
                S0y = __shfl(uy, 0);
                if (quarter > 1) { S0x += __shfl(ux, 1); S0y += __shfl(uy, 1); }
                if (quarter > 2) { S0x += __shfl(ux, 2); S0y += __shfl(uy, 2); }
            }

            // per-wave incoming state v = P_w * S0 + Pc_w ; lanes 0..11
            if (lane < NWAVE) {
                const float4 pm = sPm[f][lane];
                sv[lane] = make_float2(
                    fmaf(pm.x, S0x, fmaf(pm.y, S0y, Pc0)),
                    fmaf(pm.z, S0x, fmaf(pm.w, S0y, Pc1)));
            }
            if (lane == 0) {
                __hip_atomic_store(&sflag[f], tag, __ATOMIC_RELEASE,
                                   __HIP_MEMORY_SCOPE_WORKGROUP);
            }
        } else {
            // ready-flag spin replaces bar2
            while (__hip_atomic_load(&sflag[f], __ATOMIC_ACQUIRE,
                                     __HIP_MEMORY_SCOPE_WORKGROUP) != tag)
                __builtin_amdgcn_s_sleep(1);
        }

        const float2 v = sv[wave];

        // distribute: ic = M^lane * v + ce, via D (M^(l4)), G (M^16), P (M^32)
        float w0 = fmaf(d00, v.x, d01 * v.y);
        float w1 = fmaf(d10, v.x, d11 * v.y);
        if (lane & 16) {
            const float n0 = fmaf(g00, w0, g01 * w1);
            const float n1 = fmaf(g10, w0, g11 * w1);
            w0 = n0; w1 = n1;
        }
        if (lane & 32) {
            const float n0 = fmaf(p00, w0, p01 * w1);
            const float n1 = fmaf(p10, w0, p11 * w1);
            w0 = n0; w1 = n1;
        }
        float ic1 = w0 + ce0;
        float ic2 = w1 + ce1;

        // Phase C (+ fused next-stage Phase A)
        const float2 qc = *(const float2*)&sc[f][frame][6];
        const float c0 = qc.x, c1 = qc.y;

        if (f < NB - 1) {
            const float4 qn = *(const float4*)&sc[f + 1][frame][0];
            const float2 qb = *(const float2*)&sc[f + 1][frame][4];
            const float nt00 = qn.x, nt01 = qn.y, nt10 = qn.z, nt11 = qn.w;
            const float nb0 = qb.x, nb1 = qb.y;
            ja = 0.0f; jb = 0.0f;
            FOREACH_S(STEPF)
            tc00 = nt00; tc01 = nt01; tc10 = nt10; tc11 = nt11;
            bc0 = nb0; bc1 = nb1;
        } else {
            FOREACH_S(STEPC)
        }
    }

    // ---------------- store (with output gain) ----------------
    {
        const float og = sgain[1][frame];
        float* base = out + (size_t)bt * S + (size_t)(quarter * NCH + t) * CHUNK;
        float4 q;
        q.x = s00*og; q.y = s01*og; q.z = s02*og; q.w = s03*og; *(float4*)(base +  0) = q;
        q.x = s04*og; q.y = s05*og; q.z = s06*og; q.w = s07*og; *(float4*)(base +  4) = q;
        q.x = s08*og; q.y = s09*og; q.z = s10*og; q.w = s11*og; *(float4*)(base +  8) = q;
        q.x = s12*og; q.y = s13*og; q.z = s14*og; q.w = s15*og; *(float4*)(base + 12) = q;
    }
}

extern "C" void kernel_launch(void* const* d_in, const int* in_sizes, int n_in,
                              void* d_out, int out_size, void* d_ws, size_t ws_size,
                              hipStream_t stream)
{
    const float* audio  = (const float*)d_in[0];
    const float* params = (const float*)d_in[1];
    float* out = (float*)d_out;
    unsigned int* ws = (unsigned int*)d_ws;
    biquad_chain_kernel<<<NBLK * NBATCH, NCH, 0, stream>>>(audio, params, out, ws);
}